// Round 7
// baseline (337.405 us; speedup 1.0000x reference)
//
#include <hip/hip_runtime.h>

// SSM4D: causal depthwise conv1d, B=16, C=1024, T=3000, K=24, fp32.
// y[b,c,t] = sum_{d=0..23} w[c][d] * x[b,c,t-d],  w[c][d] = kern[c][K-1-d]
//
// R9: persistent row-streaming. R8 (read-once LDS staging, one row/block) won
// (-13us) but still pays a serial {launch -> reg-roundtrip loads -> barrier ->
// compute} chain per row-block x 64 generations/CU. Now: 4096 blocks x 4 rows,
// LDS DOUBLE-buffer, staging via global_load_lds width=16 (hardware async --
// immune to the register-allocator load-sinking that killed R7's pipeline).
// Per row: issue next row's stage, compute current row, __syncthreads()
// (compiler-emitted vmcnt drain = the fence). T3 minimum-2-phase template.
// PPOS padding dropped: dense stride-16B lane pattern on ds_read_b128 is
// conflict-free (contiguous 1024B/wave); padding only wasted LDS.
// Stores regular float4 (R7: nt-stores tripled WRITE_SIZE -- falsified).
// Roofline: ~100-197MB fetch + ~194MB write -> ~50-62us @ 6.3 TB/s.

#define KSZ   24
#define T_LEN 3000
#define C_CH  1024
#define B_N   16
#define TPB   256
#define OPT   4
#define TILE  (TPB * OPT)          // 1024
#define CHK   (T_LEN / 4)          // 750 float4 chunks per row
#define PADC  (KSZ / 4)            // 6 front zero-pad chunks
#define NCHK  (CHK + PADC)         // 756 chunks per buffer = 12.1 KB
#define RPB   4                    // rows per block
#define NBLK  ((B_N * C_CH) / RPB) // 4096 blocks

typedef float f32x4 __attribute__((ext_vector_type(4)));

__device__ __forceinline__ float cos_approx(float v) {
    float v2 = v * v;
    return 1.0f - 0.5f * v2 + (v2 * v2) * (1.0f / 24.0f);
}

// async global->LDS, 16B per lane. LDS dest is wave-uniform base + lane*16
// (HW takes base from first active lane); our linear chunk layout matches.
__device__ __forceinline__ void gload16(const float* g, float* l) {
    __builtin_amdgcn_global_load_lds(
        (const __attribute__((address_space(1))) void*)g,
        (__attribute__((address_space(3))) void*)l,
        16, 0, 0);
}

__device__ __forceinline__ void stage_row(const float* xr, f32x4* buf, int tid) {
    gload16(xr + tid * 4,             (float*)&buf[PADC + tid]);
    gload16(xr + (tid + TPB) * 4,     (float*)&buf[PADC + TPB + tid]);
    if (tid + 2 * TPB < CHK)          // tid<238: chunks 512..749
        gload16(xr + (tid + 2 * TPB) * 4, (float*)&buf[PADC + 2 * TPB + tid]);
}

__device__ __forceinline__ void calc_w(const float* __restrict__ alpha,
                                       const float* __restrict__ beta,
                                       const float* __restrict__ theta,
                                       int row, float* wsrow, int tid) {
    if (tid < KSZ) {
        const int c = row & (C_CH - 1);
        const int k = (KSZ - 1) - tid;                    // flip for causal FIR
        const float a = fmaxf(alpha[c], 1e-6f);
        wsrow[tid] = beta[c] * expf(logf(a) * (float)k)
                   * cos_approx(theta[c] * (float)k);     // bit-identical formula
    }
}

__global__ __launch_bounds__(TPB) void ssm4d_conv(
        const float* __restrict__ x,
        const float* __restrict__ alpha,
        const float* __restrict__ beta,
        const float* __restrict__ theta,
        float* __restrict__ y) {
    const int tid  = threadIdx.x;
    const int row0 = blockIdx.x * RPB;

    __shared__ f32x4 buf[2][NCHK];
    __shared__ float ws[2][KSZ];

    // causal zero front-pad, both buffers, written once (staging never touches it)
    if (tid < PADC) {
        buf[0][tid] = (f32x4){0.f, 0.f, 0.f, 0.f};
        buf[1][tid] = (f32x4){0.f, 0.f, 0.f, 0.f};
    }

    // prologue: stage row0 into buf[0]; weights under load latency
    stage_row(x + (long)row0 * T_LEN, buf[0], tid);
    calc_w(alpha, beta, theta, row0, ws[0], tid);
    __syncthreads();                       // compiler drains vmcnt before s_barrier

    int cur = 0;
#pragma unroll 1
    for (int r = 0; r < RPB; ++r) {
        const int nxt = cur ^ 1;

        // phase 1: issue next row's async stage (lands in buf[nxt] while we compute)
        if (r + 1 < RPB) {
            stage_row(x + (long)(row0 + r + 1) * T_LEN, buf[nxt], tid);
            calc_w(alpha, beta, theta, row0 + r + 1, ws[nxt], tid);
        }

        // phase 2: compute row r from buf[cur]
        float wr[KSZ];
#pragma unroll
        for (int d = 0; d < KSZ; ++d) wr[d] = ws[cur][d];  // uniform-addr broadcast

        float* yr = y + (long)(row0 + r) * T_LEN;
#pragma unroll
        for (int s = 0; s < 3; ++s) {
            const int t = s * TILE + tid * OPT;            // first output
            if (t < T_LEN) {                               // tile-2 tail idle
                const int L0 = s * (TILE / 4) + tid;       // window chunks L0..L0+6
                float win[KSZ + OPT];                      // win[p] = x[t-24+p]
#pragma unroll
                for (int q = 0; q < (KSZ + OPT) / 4; ++q) {
                    f32x4 v = buf[cur][L0 + q];            // dense: conflict-free
                    win[4 * q + 0] = v.x; win[4 * q + 1] = v.y;
                    win[4 * q + 2] = v.z; win[4 * q + 3] = v.w;
                }
                float acc[OPT];
#pragma unroll
                for (int m = 0; m < OPT; ++m) acc[m] = 0.0f;
#pragma unroll
                for (int d = 0; d < KSZ; ++d) {
#pragma unroll
                    for (int m = 0; m < OPT; ++m)
                        acc[m] = fmaf(wr[d], win[KSZ + m - d], acc[m]);
                }
                *(float4*)(yr + t) = make_float4(acc[0], acc[1], acc[2], acc[3]);
            }
        }

        // fence: stage complete (vmcnt drain) + all waves done reading buf[cur]
        __syncthreads();
        cur = nxt;
    }
}

extern "C" void kernel_launch(void* const* d_in, const int* in_sizes, int n_in,
                              void* d_out, int out_size, void* d_ws, size_t ws_size,
                              hipStream_t stream) {
    const float* x     = (const float*)d_in[0];
    const float* alpha = (const float*)d_in[1];
    const float* beta  = (const float*)d_in[2];
    const float* theta = (const float*)d_in[3];
    float* y = (float*)d_out;

    ssm4d_conv<<<NBLK, TPB, 0, stream>>>(x, alpha, beta, theta, y);
}

// Round 8
// 336.586 us; speedup vs baseline: 1.0024x; 1.0024x over previous
//
#include <hip/hip_runtime.h>

// SSM4D: causal depthwise conv1d, B=16, C=1024, T=3000, K=24, fp32.
// y[b,c,t] = sum_{d=0..23} w[c][d] * x[b,c,t-d],  w[c][d] = kern[c][K-1-d]
//
// R10: discriminating probe. R8 (reg-staged LDS, one-shot) == R9 (async
// gload_lds, persistent dbuf) == ~89us conv -> stage/pipelining falsified.
// Shared suspects: (a) compute phase: 84 wave-ds_read_b128/row (7x window
// amplification at OPT=4) + 3-tile addressing ~= 27us DS-pipe + 15us FMA;
// (b) HBM mixed-stream efficiency cap ~3.4 TB/s (301MB/89us).
// This kernel keeps the global pattern IDENTICAL and cuts (a): OPT=12 ->
// window = 36 floats = 9 CONTIGUOUS chunks/thread (amp 7x->3x, DS instrs
// 84->36/row), single tile, 288 straight-line FMAs, 3 float4 stores.
// Pre-committed read: conv 60-72us => (a) was the limiter; neutral => (b),
// declare roofline. VGPR ~72 core; __launch_bounds__(256,4) caps at 128
// (16 waves/CU) and prevents the 2-wave cliff.
// gload16 pattern (per-lane ptr, masked tail wave) is R9-verified.

#define KSZ   24
#define T_LEN 3000
#define C_CH  1024
#define B_N   16
#define TPB   256
#define OPT   12                   // outputs per thread
#define ACT   (T_LEN / OPT)        // 250 active compute threads
#define CHK   (T_LEN / 4)          // 750 float4 chunks per row
#define PADC  (KSZ / 4)            // 6 front zero-pad chunks
#define NCHK  (CHK + PADC)         // 756 chunks = 12.1 KB
#define WIN   (KSZ + OPT)          // 36-float window = 9 chunks

typedef float f32x4 __attribute__((ext_vector_type(4)));

__device__ __forceinline__ float cos_approx(float v) {
    float v2 = v * v;
    return 1.0f - 0.5f * v2 + (v2 * v2) * (1.0f / 24.0f);
}

// async global->LDS, 16B per lane (R9-verified incl. masked partial wave)
__device__ __forceinline__ void gload16(const float* g, float* l) {
    __builtin_amdgcn_global_load_lds(
        (const __attribute__((address_space(1))) void*)g,
        (__attribute__((address_space(3))) void*)l,
        16, 0, 0);
}

__global__ __launch_bounds__(TPB, 4) void ssm4d_conv(
        const float* __restrict__ x,
        const float* __restrict__ alpha,
        const float* __restrict__ beta,
        const float* __restrict__ theta,
        float* __restrict__ y) {
    const int row   = blockIdx.x;            // b*C + c
    const int c     = row & (C_CH - 1);
    const long base = (long)row * T_LEN;
    const int tid   = threadIdx.x;

    __shared__ f32x4 buf[NCHK];
    __shared__ float ws[KSZ];

    // stage the row: 750 chunks, read exactly once, async into LDS
    const float* xr = x + base;
    gload16(xr + tid * 4,             (float*)&buf[PADC + tid]);
    gload16(xr + (tid + TPB) * 4,     (float*)&buf[PADC + TPB + tid]);
    if (tid + 2 * TPB < CHK)          // tid<238: chunks 512..749
        gload16(xr + (tid + 2 * TPB) * 4, (float*)&buf[PADC + 2 * TPB + tid]);

    // under load latency: weights (bit-identical formula) + causal zero pad
    if (tid < KSZ) {
        const int k = (KSZ - 1) - tid;                    // flip for causal FIR
        const float a = fmaxf(alpha[c], 1e-6f);
        ws[tid] = beta[c] * expf(logf(a) * (float)k)
                * cos_approx(theta[c] * (float)k);
    }
    if (tid < PADC) buf[tid] = (f32x4){0.f, 0.f, 0.f, 0.f};

    __syncthreads();                  // compiler drains vmcnt+lgkm before barrier

    if (tid < ACT) {                  // 250 threads; wave-3 tail (58..63) idle
        float wr[KSZ];
#pragma unroll
        for (int d = 0; d < KSZ; ++d) wr[d] = ws[d];      // uniform-addr broadcast

        // window win[p] = x[t-24+p], p=0..35; logical chunks 3*tid .. 3*tid+8
        // (contiguous 144B per thread; lane stride 48B ~= 2-way, near-free)
        float win[WIN];
        const f32x4* wp = &buf[3 * tid];
#pragma unroll
        for (int q = 0; q < WIN / 4; ++q) {
            f32x4 v = wp[q];
            win[4 * q + 0] = v.x; win[4 * q + 1] = v.y;
            win[4 * q + 2] = v.z; win[4 * q + 3] = v.w;
        }

        float acc[OPT];
#pragma unroll
        for (int m = 0; m < OPT; ++m) acc[m] = 0.0f;
#pragma unroll
        for (int d = 0; d < KSZ; ++d) {
#pragma unroll
            for (int m = 0; m < OPT; ++m)
                acc[m] = fmaf(wr[d], win[KSZ + m - d], acc[m]);  // y[t+m]+=w[d]x[t+m-d]
        }

        const int t = tid * OPT;                          // 0..2988, +11 = 2999
        float* yr = y + base + t;
        *(float4*)(yr + 0) = make_float4(acc[0], acc[1], acc[2],  acc[3]);
        *(float4*)(yr + 4) = make_float4(acc[4], acc[5], acc[6],  acc[7]);
        *(float4*)(yr + 8) = make_float4(acc[8], acc[9], acc[10], acc[11]);
    }
}

extern "C" void kernel_launch(void* const* d_in, const int* in_sizes, int n_in,
                              void* d_out, int out_size, void* d_ws, size_t ws_size,
                              hipStream_t stream) {
    const float* x     = (const float*)d_in[0];
    const float* alpha = (const float*)d_in[1];
    const float* beta  = (const float*)d_in[2];
    const float* theta = (const float*)d_in[3];
    float* y = (float*)d_out;

    ssm4d_conv<<<B_N * C_CH, TPB, 0, stream>>>(x, alpha, beta, theta, y);
}

// Round 9
// 334.859 us; speedup vs baseline: 1.0076x; 1.0052x over previous
//
#include <hip/hip_runtime.h>

// SSM4D: causal depthwise conv1d, B=16, C=1024, T=3000, K=24, fp32.
// y[b,c,t] = sum_{d=0..23} w[c][d] * x[b,c,t-d],  w[c][d] = kern[c][K-1-d]
//
// R11: static double-buffer pipeline. R9 (buf[2][...] + runtime cur^1) was
// neutral vs unpipelined R8 -- suspected cause: runtime buffer index defeats
// LDS alias analysis, so the compiler must emit s_waitcnt vmcnt(0) before
// compute's first ds_read (can't prove gload_lds->buf[nxt] doesn't overlap
// reads of buf[cur]) => overlap collapses to zero, every row pays the full
// exposed HBM latency (the missing ~2x vs the 45-60us model; conv at 3.3TB/s
// while the m13 copy proves 6.3 mixed). Fix: compile-time-distinct bufA/bufB
// arrays + fully unrolled even/odd bodies, weights for all 4 rows hoisted to
// the prologue (zero per-iteration ds_writes). Residual vmcnt drain sits at
// the post-compute __syncthreads, hidden under ~700cy of FMAs.
// 4096 blocks x 4 rows; LDS 2x12.1KB -> 6 blocks/CU (R10 showed 4 vs 8
// blocks/CU is perf-neutral here). OPT=4 3-tile compute (VGPR ~40-64).

#define KSZ   24
#define T_LEN 3000
#define C_CH  1024
#define B_N   16
#define TPB   256
#define OPT   4
#define TILE  (TPB * OPT)          // 1024
#define CHK   (T_LEN / 4)          // 750 float4 chunks per row
#define PADC  (KSZ / 4)            // 6 front zero-pad chunks
#define NCHK  (CHK + PADC)         // 756 chunks = 12.1 KB per buffer
#define RPB   4                    // rows per block
#define NBLK  ((B_N * C_CH) / RPB) // 4096 blocks

typedef float f32x4 __attribute__((ext_vector_type(4)));

__device__ __forceinline__ float cos_approx(float v) {
    float v2 = v * v;
    return 1.0f - 0.5f * v2 + (v2 * v2) * (1.0f / 24.0f);
}

// async global->LDS, 16B per lane (R9/R10-verified incl. masked partial wave)
__device__ __forceinline__ void gload16(const float* g, float* l) {
    __builtin_amdgcn_global_load_lds(
        (const __attribute__((address_space(1))) void*)g,
        (__attribute__((address_space(3))) void*)l,
        16, 0, 0);
}

__device__ __forceinline__ void stage_row(const float* xr, f32x4* buf, int tid) {
    gload16(xr + tid * 4,             (float*)&buf[PADC + tid]);
    gload16(xr + (tid + TPB) * 4,     (float*)&buf[PADC + TPB + tid]);
    if (tid + 2 * TPB < CHK)          // tid<238: chunks 512..749
        gload16(xr + (tid + 2 * TPB) * 4, (float*)&buf[PADC + 2 * TPB + tid]);
}

// 3 tiles of 1024 outputs from a staged row buffer (dense, conflict-free)
__device__ __forceinline__ void compute_row(const f32x4* buf, const float* wsrow,
                                            float* __restrict__ yr, int tid) {
    float wr[KSZ];
#pragma unroll
    for (int d = 0; d < KSZ; ++d) wr[d] = wsrow[d];       // uniform-addr broadcast
#pragma unroll
    for (int s = 0; s < 3; ++s) {
        const int t = s * TILE + tid * OPT;               // first output
        if (t < T_LEN) {                                  // tile-2 tail idle
            const int L0 = s * (TILE / 4) + tid;          // window chunks L0..L0+6
            float win[KSZ + OPT];                         // win[p] = x[t-24+p]
#pragma unroll
            for (int q = 0; q < (KSZ + OPT) / 4; ++q) {
                f32x4 v = buf[L0 + q];
                win[4 * q + 0] = v.x; win[4 * q + 1] = v.y;
                win[4 * q + 2] = v.z; win[4 * q + 3] = v.w;
            }
            float acc[OPT];
#pragma unroll
            for (int m = 0; m < OPT; ++m) acc[m] = 0.0f;
#pragma unroll
            for (int d = 0; d < KSZ; ++d) {
#pragma unroll
                for (int m = 0; m < OPT; ++m)
                    acc[m] = fmaf(wr[d], win[KSZ + m - d], acc[m]);
            }
            *(float4*)(yr + t) = make_float4(acc[0], acc[1], acc[2], acc[3]);
        }
    }
}

__global__ __launch_bounds__(TPB) void ssm4d_conv(
        const float* __restrict__ x,
        const float* __restrict__ alpha,
        const float* __restrict__ beta,
        const float* __restrict__ theta,
        float* __restrict__ y) {
    const int tid  = threadIdx.x;
    const int row0 = blockIdx.x * RPB;

    __shared__ f32x4 bufA[NCHK];       // static, distinct arrays: alias analysis
    __shared__ f32x4 bufB[NCHK];       // can prove stage(B) independent of read(A)
    __shared__ float wsAll[RPB][KSZ];

    // prologue: stage row0 into A; all 4 rows' weights + causal pads under latency
    stage_row(x + (long)row0 * T_LEN, bufA, tid);
    if (tid < RPB * KSZ) {             // 96 threads, bit-identical formula
        const int r = tid / KSZ;
        const int k = (KSZ - 1) - (tid - r * KSZ);        // flip for causal FIR
        const int c = (row0 + r) & (C_CH - 1);
        const float a = fmaxf(alpha[c], 1e-6f);
        wsAll[r][tid - r * KSZ] = beta[c] * expf(logf(a) * (float)k)
                                * cos_approx(theta[c] * (float)k);
    }
    if (tid < PADC) {                  // staging never touches the pads
        bufA[tid] = (f32x4){0.f, 0.f, 0.f, 0.f};
        bufB[tid] = (f32x4){0.f, 0.f, 0.f, 0.f};
    }
    __syncthreads();                   // drains stage(A) + weights

    const float* xb = x + (long)row0 * T_LEN;
    float*       yb = y + (long)row0 * T_LEN;

#pragma unroll 1
    for (int it = 0; it < RPB / 2; ++it) {
        const int r0 = 2 * it;
        // body A: overlap stage(B, r0+1) with compute(A, r0)
        stage_row(xb + (long)(r0 + 1) * T_LEN, bufB, tid);
        compute_row(bufA, wsAll[r0], yb + (long)r0 * T_LEN, tid);
        __syncthreads();               // vmcnt drain (residual) + A-readers done
        // body B: overlap stage(A, r0+2) with compute(B, r0+1)
        if (r0 + 2 < RPB)
            stage_row(xb + (long)(r0 + 2) * T_LEN, bufA, tid);
        compute_row(bufB, wsAll[r0 + 1], yb + (long)(r0 + 1) * T_LEN, tid);
        __syncthreads();
    }
}

extern "C" void kernel_launch(void* const* d_in, const int* in_sizes, int n_in,
                              void* d_out, int out_size, void* d_ws, size_t ws_size,
                              hipStream_t stream) {
    const float* x     = (const float*)d_in[0];
    const float* alpha = (const float*)d_in[1];
    const float* beta  = (const float*)d_in[2];
    const float* theta = (const float*)d_in[3];
    float* y = (float*)d_out;

    ssm4d_conv<<<NBLK, TPB, 0, stream>>>(x, alpha, beta, theta, y);
}